// Round 5
// baseline (153.667 us; speedup 1.0000x reference)
//
#include <hip/hip_runtime.h>
#include <hip/hip_bf16.h>

// FC_KANLayer: B=6, T=1024, D_IN=256, D_OUT=512, NUM_GRIDS=8
// FUNC_LIST = [rbf, bs, dog, base, rbf, bs]
// f32 in/out; GEMMs via bf16 MFMA.
// R17 = R16 with k2 split by role:
//  k2a: GEMMs only (48 KiB LDS, depth-3 pipeline unchanged); spline index
//       transposed so all 8 nt-tiles of one A-panel share an XCD (L2 reuse).
//  k2b: DoG only, ZERO LDS -> ~16 waves/CU (VGPR-bound), param prefetch.
// Rationale: R16 counters showed 1.5 waves/SIMD (48 KiB forced on DoG blocks)
// => VMEM-latency-exposed DoG pinned k2 at ~50 us regardless of GEMM shape.

typedef short short8 __attribute__((ext_vector_type(8)));
typedef float floatx4 __attribute__((ext_vector_type(4)));

using bf16 = __hip_bfloat16;

#define LOG2E 1.44269504088896340736f
// c = sqrt(0.5*log2(e)); exp(-0.5 x^2) = exp2(-(c x)^2)
#define DOG_C  0.84932180028801904f
#define DOG_IC 1.17741002251547466f   // 1/c

constexpr int Tn   = 1024;
constexpr int DIN  = 256;
constexpr int DOUT = 512;
constexpr int NG   = 8;
constexpr int KSP  = DIN * NG;            // 2048
constexpr float INV_DENOM = 7.0f / 3.0f;  // 1/DENOM, DENOM = 3/7

__device__ __forceinline__ unsigned int bf16bits(float v) {
    return (unsigned int)__builtin_bit_cast(unsigned short, __float2bfloat16(v));
}
__device__ __forceinline__ float frombits(unsigned int u) {
    return __builtin_bit_cast(float, u);
}

// ================= K1 ========================================================
// [0,1536): LN+basis wave-per-row | [1536,2112): f32->bf16 convert (x8 vec)
// [2112,2176): dog-param pack into [DIN/8][DOUT][8] (pre-scaled by DOG_C)
__global__ __launch_bounds__(256) void k1_kernel(
        const float* __restrict__ X,
        const float* __restrict__ w,
        const float* __restrict__ b,
        const float* __restrict__ grid_rbf,
        const float* __restrict__ grid_bs,
        const float* __restrict__ sw,
        const float* __restrict__ bw,
        const float* __restrict__ sc,
        const float* __restrict__ tr,
        bf16* __restrict__ Amat,            // [4096][2048]
        bf16* __restrict__ Sm,              // [1024][256]
        float* __restrict__ Xn2,            // [1024][256]
        bf16* __restrict__ swb,             // [512][2048]
        bf16* __restrict__ bwb,             // [512][256]
        unsigned int* __restrict__ roP,     // [32][512][8] packed bf16 (c/s, -c*t/s)
        unsigned short* __restrict__ wnP) { // [32][512][8] bf16 (-bw/c)
    int tid = threadIdx.x, bid = blockIdx.x;

    if (bid >= 2112) {
        // ---- pack role: one thread per (dblk, dout) ------------------------
        int task = (bid - 2112) * 256 + tid;     // [0, 16384)
        int dout = task & 511, dblk = task >> 9; // dblk in [0,32)
        int base = dout * DIN + dblk * 8;
        float4 s0 = *(const float4*)&sc[base];
        float4 s1 = *(const float4*)&sc[base + 4];
        float4 t0v = *(const float4*)&tr[base];
        float4 t1v = *(const float4*)&tr[base + 4];
        float4 b0v = *(const float4*)&bw[base];
        float4 b1v = *(const float4*)&bw[base + 4];
        float vs[8] = {s0.x, s0.y, s0.z, s0.w, s1.x, s1.y, s1.z, s1.w};
        float vt[8] = {t0v.x, t0v.y, t0v.z, t0v.w, t1v.x, t1v.y, t1v.z, t1v.w};
        float vb[8] = {b0v.x, b0v.y, b0v.z, b0v.w, b1v.x, b1v.y, b1v.z, b1v.w};
        unsigned int ro_[8];
        unsigned short wn_[8];
        #pragma unroll
        for (int k = 0; k < 8; k++) {
            float inv = DOG_C / vs[k];
            ro_[k] = bf16bits(inv) | (bf16bits(-vt[k] * inv) << 16);
            wn_[k] = (unsigned short)bf16bits(-vb[k] * DOG_IC);
        }
        size_t obase = ((size_t)dblk * 512 + dout) * 8;
        uint4 r0; r0.x = ro_[0]; r0.y = ro_[1]; r0.z = ro_[2]; r0.w = ro_[3];
        uint4 r1; r1.x = ro_[4]; r1.y = ro_[5]; r1.z = ro_[6]; r1.w = ro_[7];
        *(uint4*)&roP[obase]     = r0;
        *(uint4*)&roP[obase + 4] = r1;
        uint4 wv_;
        wv_.x = (unsigned int)wn_[0] | ((unsigned int)wn_[1] << 16);
        wv_.y = (unsigned int)wn_[2] | ((unsigned int)wn_[3] << 16);
        wv_.z = (unsigned int)wn_[4] | ((unsigned int)wn_[5] << 16);
        wv_.w = (unsigned int)wn_[6] | ((unsigned int)wn_[7] << 16);
        *(uint4*)&wnP[obase] = wv_;
        return;
    }
    if (bid >= 1536) {
        // ---- convert role ---------------------------------------------------
        int e = ((bid - 1536) * 256 + tid) * 8;    // [0, 1179648)
        const float* src = (e < 1048576) ? (sw + e) : (bw + (e - 1048576));
        bf16* dst = (e < 1048576) ? (swb + e) : (bwb + (e - 1048576));
        float4 v0 = *(const float4*)src;
        float4 v1 = *(const float4*)(src + 4);
        short8 p;
        p[0] = __builtin_bit_cast(short, __float2bfloat16(v0.x));
        p[1] = __builtin_bit_cast(short, __float2bfloat16(v0.y));
        p[2] = __builtin_bit_cast(short, __float2bfloat16(v0.z));
        p[3] = __builtin_bit_cast(short, __float2bfloat16(v0.w));
        p[4] = __builtin_bit_cast(short, __float2bfloat16(v1.x));
        p[5] = __builtin_bit_cast(short, __float2bfloat16(v1.y));
        p[6] = __builtin_bit_cast(short, __float2bfloat16(v1.z));
        p[7] = __builtin_bit_cast(short, __float2bfloat16(v1.w));
        *(short8*)dst = p;
        return;
    }

    // ---- LN + basis role ----------------------------------------------------
    int wv = tid >> 6, lane = tid & 63;
    int row = bid * 4 + wv;              // b*1024 + t
    int batch = row >> 10, t = row & 1023;

    float x[4];
    #pragma unroll
    for (int j = 0; j < 4; j++) x[j] = X[(size_t)row * DIN + j * 64 + lane];
    float s = x[0] + x[1] + x[2] + x[3];
    float ss = x[0] * x[0] + x[1] * x[1] + x[2] * x[2] + x[3] * x[3];
    #pragma unroll
    for (int o = 1; o < 64; o <<= 1) {
        s  += __shfl_xor(s, o);
        ss += __shfl_xor(ss, o);
    }
    float mu = s * (1.0f / DIN);
    float rstd = rsqrtf(ss * (1.0f / DIN) - mu * mu + 1e-5f);

    float xn[4];
    #pragma unroll
    for (int j = 0; j < 4; j++) {
        int din = j * 64 + lane;
        xn[j] = (x[j] - mu) * rstd * w[din] + b[din];
    }

    if (batch == 2) {
        #pragma unroll
        for (int j = 0; j < 4; j++)
            Xn2[(size_t)t * DIN + j * 64 + lane] = xn[j];
    } else if (batch == 3) {
        #pragma unroll
        for (int j = 0; j < 4; j++) {
            float e = __builtin_amdgcn_exp2f(-xn[j] * LOG2E);
            float si = xn[j] * __builtin_amdgcn_rcpf(1.0f + e);
            Sm[(size_t)t * DIN + j * 64 + lane] = __float2bfloat16(si);
        }
    } else {
        int which = (batch == 0) ? 0 : (batch == 1) ? 1 : (batch == 4) ? 2 : 3;
        bool is_rbf = (batch == 0) || (batch == 4);
        #pragma unroll
        for (int j = 0; j < 4; j++) {
            float v = xn[j];
            float outv[NG];
            if (is_rbf) {
                #pragma unroll
                for (int g = 0; g < NG; g++) {
                    float d = (v - grid_rbf[g]) * INV_DENOM;
                    outv[g] = __builtin_amdgcn_exp2f(-d * d * LOG2E);
                }
            } else {
                float g[12];
                #pragma unroll
                for (int i = 0; i < 12; i++) g[i] = grid_bs[i];
                float ih = 1.0f / (g[1] - g[0]);
                float ihk[3] = {ih, ih * 0.5f, ih * (1.0f / 3.0f)};
                float bs_[11];
                #pragma unroll
                for (int i = 0; i < 11; i++)
                    bs_[i] = (v >= g[i] && v < g[i + 1]) ? 1.0f : 0.0f;
                #pragma unroll
                for (int k = 1; k <= 3; k++) {
                    float rk = ihk[k - 1];
                    #pragma unroll
                    for (int i = 0; i < 10; i++) {
                        if (i <= 10 - k) {
                            bs_[i] = (v - g[i]) * rk * bs_[i]
                                   + (g[i + k + 1] - v) * rk * bs_[i + 1];
                        }
                    }
                }
                #pragma unroll
                for (int gg = 0; gg < NG; gg++) outv[gg] = bs_[gg];
            }
            short8 pv;
            #pragma unroll
            for (int gg = 0; gg < NG; gg++)
                pv[gg] = __builtin_bit_cast(short, __float2bfloat16(outv[gg]));
            *(short8*)((short*)Amat + (size_t)(which * Tn + t) * KSP
                       + (size_t)(j * 64 + lane) * NG) = pv;
        }
    }
}

// ---------------- GEMM core: 128x64 tile, 2 waves, BK=32, 4-buf depth-3 ------
// Wave wv owns rows [wv*64, wv*64+64) x all 64 cols: 4x4 16x16 frags.
// Per wave-K-step: 8 ds_read_b128 : 16 MFMA (balanced). 6 global_load_lds
// per wave per tile; waits are counted (vmcnt(12)/6/0), never drained early.
template <int KS>
__device__ __forceinline__ void gemm_128x64(const short* __restrict__ A,
                                            const short* __restrict__ Bw,
                                            int row0, int col0, int iters,
                                            int tid, char* smem, floatx4 acc[4][4]) {
    short* ldsA = (short*)smem;             // [4][128][32] = 32 KiB
    short* ldsB = (short*)(smem + 32768);   // [4][64][32]  = 16 KiB
    int wv = tid >> 6, lane = tid & 63;
    int r16 = lane >> 2, cs = lane & 3;
    // A staging: wave wv covers rows [wv*64, wv*64+64), 4 issues of 16 rows.
    // Source pre-swizzled: physical chunk p of row r holds global chunk
    // p ^ ((r>>1)&3); LDS dest stays linear (wave-uniform base + lane*16B).
    const short* gA[4]; int dA[4];
    #pragma unroll
    for (int p = 0; p < 4; p++) {
        int sr = wv * 64 + p * 16 + r16;
        int cg = cs ^ ((sr >> 1) & 3);
        gA[p] = A + (size_t)(row0 + sr) * KS + cg * 8;
        dA[p] = (wv * 64 + p * 16) * 32;
    }
    // B staging: wave wv covers rows [wv*32, wv*32+32), 2 issues.
    const short* gB[2]; int dB[2];
    #pragma unroll
    for (int p = 0; p < 2; p++) {
        int sr = wv * 32 + p * 16 + r16;
        int cg = cs ^ ((sr >> 1) & 3);
        gB[p] = Bw + (size_t)(col0 + sr) * KS + cg * 8;
        dB[p] = (wv * 32 + p * 16) * 32;
    }

    int m = lane & 15, q = lane >> 4;
    int oA[4], oB[4];
    #pragma unroll
    for (int i = 0; i < 4; i++) {
        int ra = wv * 64 + i * 16 + m;            // own-half rows only
        oA[i] = ra * 32 + (q ^ ((ra >> 1) & 3)) * 8;
        int rb = i * 16 + m;                      // all 64 B rows
        oB[i] = rb * 32 + (q ^ ((rb >> 1) & 3)) * 8;
    }

    auto issue = [&](int buf, int kof) {
        #pragma unroll
        for (int p = 0; p < 4; p++)
            __builtin_amdgcn_global_load_lds(
                (const __attribute__((address_space(1))) void*)(gA[p] + kof),
                (__attribute__((address_space(3))) void*)(ldsA + buf * 4096 + dA[p]),
                16, 0, 0);
        #pragma unroll
        for (int p = 0; p < 2; p++)
            __builtin_amdgcn_global_load_lds(
                (const __attribute__((address_space(1))) void*)(gB[p] + kof),
                (__attribute__((address_space(3))) void*)(ldsB + buf * 2048 + dB[p]),
                16, 0, 0);
    };

    issue(0, 0);
    if (iters > 1) issue(1, 32);
    if (iters > 2) issue(2, 64);
    for (int i = 0; i < iters; i++) {
        int cur = i & 3;
        int ahead = iters - i;
        // own 6 loads for tile i are the oldest; with k tiles in flight wait
        // until 6*(k-1) remain.
        if (ahead > 2) {
            asm volatile("s_waitcnt vmcnt(12)" ::: "memory");
        } else if (ahead == 2) {
            asm volatile("s_waitcnt vmcnt(6)" ::: "memory");
        } else {
            asm volatile("s_waitcnt vmcnt(0)" ::: "memory");
        }
        asm volatile("s_barrier" ::: "memory");
        if (i + 3 < iters) issue((i + 3) & 3, (i + 3) * 32);
        const short* bA = ldsA + cur * 4096;
        const short* bB = ldsB + cur * 2048;
        short8 a[4], b[4];
        #pragma unroll
        for (int r = 0; r < 4; r++) {
            a[r] = *(const short8*)(bA + oA[r]);
            b[r] = *(const short8*)(bB + oB[r]);
        }
        __builtin_amdgcn_s_setprio(1);
        #pragma unroll
        for (int r = 0; r < 4; r++)
            #pragma unroll
            for (int c = 0; c < 4; c++)
                acc[r][c] = __builtin_amdgcn_mfma_f32_16x16x32_bf16(
                    a[r], b[c], acc[r][c], 0, 0, 0);
        __builtin_amdgcn_s_setprio(0);
    }
}

// ================= K2a: GEMM-only kernel =====================================
// [0,256):   spline GEMM 128x64, K=2048. idx = nt*32 + mt so all 8 nt-tiles
//            of one A-panel share bid%8 (same XCD L2 -> A fetched once/XCD).
// [256,320): base GEMM 128x64, K=256 (idx2 = nt*8 + mt, same trick)
__global__ __launch_bounds__(128) void k2a_kernel(const bf16* __restrict__ Amat,
                                                  const bf16* __restrict__ SWb,
                                                  const bf16* __restrict__ Sm,
                                                  const bf16* __restrict__ BWb,
                                                  float* __restrict__ out) {
    __shared__ alignas(16) char smem[49152];
    int bid = blockIdx.x, tid = threadIdx.x;

    bool spline = bid < 256;
    int mt, nt;
    if (spline) { int idx = bid;        mt = idx & 31, nt = idx >> 5; }
    else        { int idx = bid - 256;  mt = idx & 7,  nt = idx >> 3; }
    int row0 = mt * 128, col0 = nt * 64;
    floatx4 acc[4][4];
    #pragma unroll
    for (int r = 0; r < 4; r++)
        #pragma unroll
        for (int c = 0; c < 4; c++) acc[r][c] = (floatx4)(0.0f);

    if (spline) {
        gemm_128x64<KSP>((const short*)Amat, (const short*)SWb,
                         row0, col0, 64, tid, smem, acc);
    } else {
        gemm_128x64<DIN>((const short*)Sm, (const short*)BWb,
                         row0, col0, 8, tid, smem, acc);
    }

    int wv = tid >> 6, lane = tid & 63;
    int m = lane & 15, q = lane >> 4;
    size_t rowbase;
    if (spline) {
        int which = row0 >> 10;              // 128-row tile within one batch
        int batch = (which == 0) ? 0 : (which == 1) ? 1 : (which == 2) ? 4 : 5;
        rowbase = (size_t)batch * Tn + (row0 & 1023);
    } else {
        rowbase = (size_t)3 * Tn + row0;
    }
    #pragma unroll
    for (int r = 0; r < 4; r++)
        #pragma unroll
        for (int c = 0; c < 4; c++)
            #pragma unroll
            for (int rr = 0; rr < 4; rr++) {
                int rloc = wv * 64 + r * 16 + q * 4 + rr;
                int col = col0 + c * 16 + m;
                out[(rowbase + rloc) * DOUT + col] = acc[r][c][rr];
            }
}

// ================= K2b: DoG-only kernel (ZERO LDS, high occupancy) ===========
// 512 blocks x 128 thr: 128 dout x 8 t per block; params double-buffered.
__global__ __launch_bounds__(128, 4) void k2b_kernel(
        const float* __restrict__ Xn2,
        const unsigned int* __restrict__ roP,
        const unsigned short* __restrict__ wnP,
        float* __restrict__ out) {
    int bid = blockIdx.x, tid = threadIdx.x;
    int dt = bid & 3, t0 = (bid >> 2) * 8;     // t0 in {0,8,...,1016}
    int dout = dt * 128 + tid;

    const unsigned int*   rop = roP + (size_t)dout * 8;
    const unsigned short* wnp = wnP + (size_t)dout * 8;
    const float* xrow[8];
    #pragma unroll
    for (int j = 0; j < 8; j++) xrow[j] = Xn2 + (size_t)(t0 + j) * DIN;

    float acc[8] = {0.f, 0.f, 0.f, 0.f, 0.f, 0.f, 0.f, 0.f};

    // prefetch first param block
    uint4 ra = *(const uint4*)rop;
    uint4 rb = *(const uint4*)(rop + 4);
    uint4 wq = *(const uint4*)wnp;

    for (int db8 = 0; db8 < 32; db8++) {
        int d = db8 * 8;
        uint4 ca = ra, cb = rb, cw = wq;
        if (db8 < 31) {
            rop += 4096;   // 512*8 uints per d-block
            wnp += 4096;   // 512*8 ushorts per d-block
            ra = *(const uint4*)rop;
            rb = *(const uint4*)(rop + 4);
            wq = *(const uint4*)wnp;
        }
        unsigned int roarr[8] = {ca.x, ca.y, ca.z, ca.w,
                                 cb.x, cb.y, cb.z, cb.w};
        unsigned int wword[4] = {cw.x, cw.y, cw.z, cw.w};
        #pragma unroll
        for (int g = 0; g < 2; g++) {
            float4 xj[8];
            #pragma unroll
            for (int j = 0; j < 8; j++)
                xj[j] = *(const float4*)&xrow[j][d + g * 4];   // broadcast
            #pragma unroll
            for (int kq = 0; kq < 4; kq++) {
                int k = g * 4 + kq;
                unsigned int rw = roarr[k];
                float r = frombits(rw << 16);
                float o = frombits(rw & 0xFFFF0000u);
                unsigned int ww = wword[k >> 1];
                float w = (k & 1) ? frombits(ww & 0xFFFF0000u)
                                  : frombits(ww << 16);
                #pragma unroll
                for (int j = 0; j < 8; j++) {
                    float xval = ((const float*)&xj[j])[kq];
                    float z = fmaf(xval, r, o);
                    float e = __builtin_amdgcn_exp2f(-(z * z));
                    acc[j] = fmaf(z * e, w, acc[j]);
                }
            }
        }
    }
    size_t base = (size_t)2 * Tn * DOUT + (size_t)t0 * DOUT + dout;
    #pragma unroll
    for (int j = 0; j < 8; j++) out[base + (size_t)j * DOUT] = acc[j];
}

extern "C" void kernel_launch(void* const* d_in, const int* in_sizes, int n_in,
                              void* d_out, int out_size, void* d_ws, size_t ws_size,
                              hipStream_t stream) {
    const float* X        = (const float*)d_in[0];
    const float* ln_w     = (const float*)d_in[1];
    const float* ln_b     = (const float*)d_in[2];
    const float* base_w   = (const float*)d_in[3];
    const float* spline_w = (const float*)d_in[4];
    const float* scale    = (const float*)d_in[5];
    const float* transl   = (const float*)d_in[6];
    const float* grid_rbf = (const float*)d_in[7];
    const float* grid_bs  = (const float*)d_in[8];
    float* out = (float*)d_out;

    char* ws = (char*)d_ws;
    bf16*  Amat = (bf16*)ws;                                   // 16 MiB   [4096][2048]
    bf16*  SWb  = (bf16*)(ws + 16777216);                      // 2 MiB    [512][2048]
    bf16*  BWb  = (bf16*)(ws + 18874368);                      // 0.25 MiB [512][256]
    bf16*  Sm   = (bf16*)(ws + 19136512);                      // 0.5 MiB  [1024][256]
    float* Xn2  = (float*)(ws + 19660800);                     // 1 MiB    [1024][256]
    unsigned int*   roP = (unsigned int*)(ws + 20709376);      // 0.5 MiB  [32][512][8]
    unsigned short* wnP = (unsigned short*)(ws + 21233664);    // 0.25 MiB [32][512][8]

    k1_kernel<<<2176, 256, 0, stream>>>(X, ln_w, ln_b, grid_rbf, grid_bs,
                                        spline_w, base_w, scale, transl,
                                        Amat, Sm, Xn2, SWb, BWb, roP, wnP);
    k2a_kernel<<<320, 128, 0, stream>>>(Amat, SWb, Sm, BWb, out);
    k2b_kernel<<<512, 128, 0, stream>>>(Xn2, roP, wnP, out);
}

// Round 6
// 126.758 us; speedup vs baseline: 1.2123x; 1.2123x over previous
//
#include <hip/hip_runtime.h>
#include <hip/hip_bf16.h>

// FC_KANLayer: B=6, T=1024, D_IN=256, D_OUT=512, NUM_GRIDS=8
// FUNC_LIST = [rbf, bs, dog, base, rbf, bs]
// f32 in/out; GEMMs via bf16 MFMA.
// R18: re-merged k2 with both R16/R17 failure modes fixed:
//  - DoG t-batch 4 -> 1024 DoG blocks (2048 waves; R17's 1024-wave grid
//    starvation was the 48.8us DoG bottleneck, Occupancy 8.4%)
//  - GEMM LDS 24 KiB (2-buffer) -> 6 blocks/CU residency so DoG waves
//    co-reside with GEMM (R16's 48 KiB forced 3 blocks/CU, 1.5 waves/SIMD)
//  - GEMM loop: wait vmcnt(0) BEFORE s_barrier (cross-wave visibility),
//    issue after barrier; per-iter stall covered by DoG VALU waves (m114).

typedef short short8 __attribute__((ext_vector_type(8)));
typedef float floatx4 __attribute__((ext_vector_type(4)));

using bf16 = __hip_bfloat16;

#define LOG2E 1.44269504088896340736f
// c = sqrt(0.5*log2(e)); exp(-0.5 x^2) = exp2(-(c x)^2)
#define DOG_C  0.84932180028801904f
#define DOG_IC 1.17741002251547466f   // 1/c

constexpr int Tn   = 1024;
constexpr int DIN  = 256;
constexpr int DOUT = 512;
constexpr int NG   = 8;
constexpr int KSP  = DIN * NG;            // 2048
constexpr float INV_DENOM = 7.0f / 3.0f;  // 1/DENOM, DENOM = 3/7

__device__ __forceinline__ unsigned int bf16bits(float v) {
    return (unsigned int)__builtin_bit_cast(unsigned short, __float2bfloat16(v));
}
__device__ __forceinline__ float frombits(unsigned int u) {
    return __builtin_bit_cast(float, u);
}

// ================= K1 ========================================================
// [0,1536): LN+basis wave-per-row | [1536,2112): f32->bf16 convert (x8 vec)
// [2112,2176): dog-param pack into [DIN/8][DOUT][8] (pre-scaled by DOG_C)
__global__ __launch_bounds__(256) void k1_kernel(
        const float* __restrict__ X,
        const float* __restrict__ w,
        const float* __restrict__ b,
        const float* __restrict__ grid_rbf,
        const float* __restrict__ grid_bs,
        const float* __restrict__ sw,
        const float* __restrict__ bw,
        const float* __restrict__ sc,
        const float* __restrict__ tr,
        bf16* __restrict__ Amat,            // [4096][2048]
        bf16* __restrict__ Sm,              // [1024][256]
        float* __restrict__ Xn2,            // [1024][256]
        bf16* __restrict__ swb,             // [512][2048]
        bf16* __restrict__ bwb,             // [512][256]
        unsigned int* __restrict__ roP,     // [32][512][8] packed bf16 (c/s, -c*t/s)
        unsigned short* __restrict__ wnP) { // [32][512][8] bf16 (-bw/c)
    int tid = threadIdx.x, bid = blockIdx.x;

    if (bid >= 2112) {
        // ---- pack role: one thread per (dblk, dout) ------------------------
        int task = (bid - 2112) * 256 + tid;     // [0, 16384)
        int dout = task & 511, dblk = task >> 9; // dblk in [0,32)
        int base = dout * DIN + dblk * 8;
        float4 s0 = *(const float4*)&sc[base];
        float4 s1 = *(const float4*)&sc[base + 4];
        float4 t0v = *(const float4*)&tr[base];
        float4 t1v = *(const float4*)&tr[base + 4];
        float4 b0v = *(const float4*)&bw[base];
        float4 b1v = *(const float4*)&bw[base + 4];
        float vs[8] = {s0.x, s0.y, s0.z, s0.w, s1.x, s1.y, s1.z, s1.w};
        float vt[8] = {t0v.x, t0v.y, t0v.z, t0v.w, t1v.x, t1v.y, t1v.z, t1v.w};
        float vb[8] = {b0v.x, b0v.y, b0v.z, b0v.w, b1v.x, b1v.y, b1v.z, b1v.w};
        unsigned int ro_[8];
        unsigned short wn_[8];
        #pragma unroll
        for (int k = 0; k < 8; k++) {
            float inv = DOG_C / vs[k];
            ro_[k] = bf16bits(inv) | (bf16bits(-vt[k] * inv) << 16);
            wn_[k] = (unsigned short)bf16bits(-vb[k] * DOG_IC);
        }
        size_t obase = ((size_t)dblk * 512 + dout) * 8;
        uint4 r0; r0.x = ro_[0]; r0.y = ro_[1]; r0.z = ro_[2]; r0.w = ro_[3];
        uint4 r1; r1.x = ro_[4]; r1.y = ro_[5]; r1.z = ro_[6]; r1.w = ro_[7];
        *(uint4*)&roP[obase]     = r0;
        *(uint4*)&roP[obase + 4] = r1;
        uint4 wv_;
        wv_.x = (unsigned int)wn_[0] | ((unsigned int)wn_[1] << 16);
        wv_.y = (unsigned int)wn_[2] | ((unsigned int)wn_[3] << 16);
        wv_.z = (unsigned int)wn_[4] | ((unsigned int)wn_[5] << 16);
        wv_.w = (unsigned int)wn_[6] | ((unsigned int)wn_[7] << 16);
        *(uint4*)&wnP[obase] = wv_;
        return;
    }
    if (bid >= 1536) {
        // ---- convert role ---------------------------------------------------
        int e = ((bid - 1536) * 256 + tid) * 8;    // [0, 1179648)
        const float* src = (e < 1048576) ? (sw + e) : (bw + (e - 1048576));
        bf16* dst = (e < 1048576) ? (swb + e) : (bwb + (e - 1048576));
        float4 v0 = *(const float4*)src;
        float4 v1 = *(const float4*)(src + 4);
        short8 p;
        p[0] = __builtin_bit_cast(short, __float2bfloat16(v0.x));
        p[1] = __builtin_bit_cast(short, __float2bfloat16(v0.y));
        p[2] = __builtin_bit_cast(short, __float2bfloat16(v0.z));
        p[3] = __builtin_bit_cast(short, __float2bfloat16(v0.w));
        p[4] = __builtin_bit_cast(short, __float2bfloat16(v1.x));
        p[5] = __builtin_bit_cast(short, __float2bfloat16(v1.y));
        p[6] = __builtin_bit_cast(short, __float2bfloat16(v1.z));
        p[7] = __builtin_bit_cast(short, __float2bfloat16(v1.w));
        *(short8*)dst = p;
        return;
    }

    // ---- LN + basis role ----------------------------------------------------
    int wv = tid >> 6, lane = tid & 63;
    int row = bid * 4 + wv;              // b*1024 + t
    int batch = row >> 10, t = row & 1023;

    float x[4];
    #pragma unroll
    for (int j = 0; j < 4; j++) x[j] = X[(size_t)row * DIN + j * 64 + lane];
    float s = x[0] + x[1] + x[2] + x[3];
    float ss = x[0] * x[0] + x[1] * x[1] + x[2] * x[2] + x[3] * x[3];
    #pragma unroll
    for (int o = 1; o < 64; o <<= 1) {
        s  += __shfl_xor(s, o);
        ss += __shfl_xor(ss, o);
    }
    float mu = s * (1.0f / DIN);
    float rstd = rsqrtf(ss * (1.0f / DIN) - mu * mu + 1e-5f);

    float xn[4];
    #pragma unroll
    for (int j = 0; j < 4; j++) {
        int din = j * 64 + lane;
        xn[j] = (x[j] - mu) * rstd * w[din] + b[din];
    }

    if (batch == 2) {
        #pragma unroll
        for (int j = 0; j < 4; j++)
            Xn2[(size_t)t * DIN + j * 64 + lane] = xn[j];
    } else if (batch == 3) {
        #pragma unroll
        for (int j = 0; j < 4; j++) {
            float e = __builtin_amdgcn_exp2f(-xn[j] * LOG2E);
            float si = xn[j] * __builtin_amdgcn_rcpf(1.0f + e);
            Sm[(size_t)t * DIN + j * 64 + lane] = __float2bfloat16(si);
        }
    } else {
        int which = (batch == 0) ? 0 : (batch == 1) ? 1 : (batch == 4) ? 2 : 3;
        bool is_rbf = (batch == 0) || (batch == 4);
        #pragma unroll
        for (int j = 0; j < 4; j++) {
            float v = xn[j];
            float outv[NG];
            if (is_rbf) {
                #pragma unroll
                for (int g = 0; g < NG; g++) {
                    float d = (v - grid_rbf[g]) * INV_DENOM;
                    outv[g] = __builtin_amdgcn_exp2f(-d * d * LOG2E);
                }
            } else {
                float g[12];
                #pragma unroll
                for (int i = 0; i < 12; i++) g[i] = grid_bs[i];
                float ih = 1.0f / (g[1] - g[0]);
                float ihk[3] = {ih, ih * 0.5f, ih * (1.0f / 3.0f)};
                float bs_[11];
                #pragma unroll
                for (int i = 0; i < 11; i++)
                    bs_[i] = (v >= g[i] && v < g[i + 1]) ? 1.0f : 0.0f;
                #pragma unroll
                for (int k = 1; k <= 3; k++) {
                    float rk = ihk[k - 1];
                    #pragma unroll
                    for (int i = 0; i < 10; i++) {
                        if (i <= 10 - k) {
                            bs_[i] = (v - g[i]) * rk * bs_[i]
                                   + (g[i + k + 1] - v) * rk * bs_[i + 1];
                        }
                    }
                }
                #pragma unroll
                for (int gg = 0; gg < NG; gg++) outv[gg] = bs_[gg];
            }
            short8 pv;
            #pragma unroll
            for (int gg = 0; gg < NG; gg++)
                pv[gg] = __builtin_bit_cast(short, __float2bfloat16(outv[gg]));
            *(short8*)((short*)Amat + (size_t)(which * Tn + t) * KSP
                       + (size_t)(j * 64 + lane) * NG) = pv;
        }
    }
}

// ---------------- GEMM core: 128x64 tile, 2 waves, BK=32, 2-buf (24 KiB) -----
// Wave wv owns rows [wv*64, wv*64+64) x all 64 cols: 4x4 16x16 frags.
// Per wave-K-step: 8 ds_read_b128 : 16 MFMA (balanced). 6 global_load_lds
// per wave per tile. Order: wait vmcnt(0) (own loads landed) -> s_barrier
// (=> ALL waves' loads landed AND prev-iter reads consumed) -> issue next
// tile into the just-freed buffer -> ds_read + MFMA. Per-iter drain stall
// is covered by co-resident DoG waves on the VALU pipe.
template <int KS>
__device__ __forceinline__ void gemm_128x64(const short* __restrict__ A,
                                            const short* __restrict__ Bw,
                                            int row0, int col0, int iters,
                                            int tid, char* smem, floatx4 acc[4][4]) {
    short* ldsA = (short*)smem;             // [2][128][32] = 16 KiB
    short* ldsB = (short*)(smem + 16384);   // [2][64][32]  = 8 KiB
    int wv = tid >> 6, lane = tid & 63;
    int r16 = lane >> 2, cs = lane & 3;
    // A staging: wave wv covers rows [wv*64, wv*64+64), 4 issues of 16 rows.
    // Source pre-swizzled: physical chunk p of row r holds global chunk
    // p ^ ((r>>1)&3); LDS dest stays linear (wave-uniform base + lane*16B).
    const short* gA[4]; int dA[4];
    #pragma unroll
    for (int p = 0; p < 4; p++) {
        int sr = wv * 64 + p * 16 + r16;
        int cg = cs ^ ((sr >> 1) & 3);
        gA[p] = A + (size_t)(row0 + sr) * KS + cg * 8;
        dA[p] = (wv * 64 + p * 16) * 32;
    }
    // B staging: wave wv covers rows [wv*32, wv*32+32), 2 issues.
    const short* gB[2]; int dB[2];
    #pragma unroll
    for (int p = 0; p < 2; p++) {
        int sr = wv * 32 + p * 16 + r16;
        int cg = cs ^ ((sr >> 1) & 3);
        gB[p] = Bw + (size_t)(col0 + sr) * KS + cg * 8;
        dB[p] = (wv * 32 + p * 16) * 32;
    }

    int m = lane & 15, q = lane >> 4;
    int oA[4], oB[4];
    #pragma unroll
    for (int i = 0; i < 4; i++) {
        int ra = wv * 64 + i * 16 + m;            // own-half rows only
        oA[i] = ra * 32 + (q ^ ((ra >> 1) & 3)) * 8;
        int rb = i * 16 + m;                      // all 64 B rows
        oB[i] = rb * 32 + (q ^ ((rb >> 1) & 3)) * 8;
    }

    auto issue = [&](int buf, int kof) {
        #pragma unroll
        for (int p = 0; p < 4; p++)
            __builtin_amdgcn_global_load_lds(
                (const __attribute__((address_space(1))) void*)(gA[p] + kof),
                (__attribute__((address_space(3))) void*)(ldsA + buf * 4096 + dA[p]),
                16, 0, 0);
        #pragma unroll
        for (int p = 0; p < 2; p++)
            __builtin_amdgcn_global_load_lds(
                (const __attribute__((address_space(1))) void*)(gB[p] + kof),
                (__attribute__((address_space(3))) void*)(ldsB + buf * 2048 + dB[p]),
                16, 0, 0);
    };

    issue(0, 0);
    for (int i = 0; i < iters; i++) {
        int cur = i & 1;
        asm volatile("s_waitcnt vmcnt(0)" ::: "memory");
        asm volatile("s_barrier" ::: "memory");
        if (i + 1 < iters) issue(cur ^ 1, (i + 1) * 32);
        const short* bA = ldsA + cur * 4096;
        const short* bB = ldsB + cur * 2048;
        short8 a[4], b[4];
        #pragma unroll
        for (int r = 0; r < 4; r++) {
            a[r] = *(const short8*)(bA + oA[r]);
            b[r] = *(const short8*)(bB + oB[r]);
        }
        __builtin_amdgcn_s_setprio(1);
        #pragma unroll
        for (int r = 0; r < 4; r++)
            #pragma unroll
            for (int c = 0; c < 4; c++)
                acc[r][c] = __builtin_amdgcn_mfma_f32_16x16x32_bf16(
                    a[r], b[c], acc[r][c], 0, 0, 0);
        __builtin_amdgcn_s_setprio(0);
    }
}

// ================= K2: merged heterogeneous kernel (128-thread blocks) =======
// [0,256):    spline GEMM 128x64, K=2048; bid = nt*32+mt so the 8 nt-tiles of
//             one A-panel all land on XCD (mt%8) -> A fetched once per L2.
// [256,320):  base GEMM 128x64, K=256
// [320,1344): DoG: 128 dout x 4 t (1024 blocks = 2048 waves; grid starvation
//             at 8t was R17's 48.8us bottleneck)
__global__ __launch_bounds__(128) void k2_kernel(const bf16* __restrict__ Amat,
                                                 const bf16* __restrict__ SWb,
                                                 const bf16* __restrict__ Sm,
                                                 const bf16* __restrict__ BWb,
                                                 const float* __restrict__ Xn2,
                                                 const unsigned int* __restrict__ roP,
                                                 const unsigned short* __restrict__ wnP,
                                                 float* __restrict__ out) {
    __shared__ alignas(16) char smem[24576];
    int bid = blockIdx.x, tid = threadIdx.x;

    if (bid < 320) {
        // ---- GEMM roles ----------------------------------------------------
        bool spline = bid < 256;
        int mt, nt;
        if (spline) { int idx = bid;        mt = idx & 31; nt = idx >> 5; }
        else        { int idx = bid - 256;  mt = idx & 7;  nt = idx >> 3; }
        int row0 = mt * 128, col0 = nt * 64;
        floatx4 acc[4][4];
        #pragma unroll
        for (int r = 0; r < 4; r++)
            #pragma unroll
            for (int c = 0; c < 4; c++) acc[r][c] = (floatx4)(0.0f);

        if (spline) {
            gemm_128x64<KSP>((const short*)Amat, (const short*)SWb,
                             row0, col0, 64, tid, smem, acc);
        } else {
            gemm_128x64<DIN>((const short*)Sm, (const short*)BWb,
                             row0, col0, 8, tid, smem, acc);
        }

        int wv = tid >> 6, lane = tid & 63;
        int m = lane & 15, q = lane >> 4;
        size_t rowbase;
        if (spline) {
            int which = row0 >> 10;              // 128-row tile within one batch
            int batch = (which == 0) ? 0 : (which == 1) ? 1 : (which == 2) ? 4 : 5;
            rowbase = (size_t)batch * Tn + (row0 & 1023);
        } else {
            rowbase = (size_t)3 * Tn + row0;
        }
        #pragma unroll
        for (int r = 0; r < 4; r++)
            #pragma unroll
            for (int c = 0; c < 4; c++)
                #pragma unroll
                for (int rr = 0; rr < 4; rr++) {
                    int rloc = wv * 64 + r * 16 + q * 4 + rr;
                    int col = col0 + c * 16 + m;
                    out[(rowbase + rloc) * DOUT + col] = acc[r][c][rr];
                }
    } else {
        // ---- DoG role: 128 dout x 4 t, zero extra LDS use ------------------
        int db = bid - 320;                      // [0,1024)
        int dt = db & 3, t0 = (db >> 2) * 4;     // t0 in {0,4,...,1020}
        int dout = dt * 128 + tid;

        const unsigned int*   rop = roP + (size_t)dout * 8;
        const unsigned short* wnp = wnP + (size_t)dout * 8;
        const float* xrow[4];
        #pragma unroll
        for (int j = 0; j < 4; j++) xrow[j] = Xn2 + (size_t)(t0 + j) * DIN;

        float acc[4] = {0.f, 0.f, 0.f, 0.f};

        // prefetch first param block
        uint4 ra = *(const uint4*)rop;
        uint4 rb = *(const uint4*)(rop + 4);
        uint4 wq = *(const uint4*)wnp;

        for (int db8 = 0; db8 < 32; db8++) {
            int d = db8 * 8;
            uint4 ca = ra, cb = rb, cw = wq;
            if (db8 < 31) {
                rop += 4096;   // 512*8 uints per d-block
                wnp += 4096;   // 512*8 ushorts per d-block
                ra = *(const uint4*)rop;
                rb = *(const uint4*)(rop + 4);
                wq = *(const uint4*)wnp;
            }
            unsigned int roarr[8] = {ca.x, ca.y, ca.z, ca.w,
                                     cb.x, cb.y, cb.z, cb.w};
            unsigned int wword[4] = {cw.x, cw.y, cw.z, cw.w};
            #pragma unroll
            for (int g = 0; g < 2; g++) {
                float4 xj[4];
                #pragma unroll
                for (int j = 0; j < 4; j++)
                    xj[j] = *(const float4*)&xrow[j][d + g * 4];   // uniform
                #pragma unroll
                for (int kq = 0; kq < 4; kq++) {
                    int k = g * 4 + kq;
                    unsigned int rw = roarr[k];
                    float r = frombits(rw << 16);
                    float o = frombits(rw & 0xFFFF0000u);
                    unsigned int ww = wword[k >> 1];
                    float w = (k & 1) ? frombits(ww & 0xFFFF0000u)
                                      : frombits(ww << 16);
                    #pragma unroll
                    for (int j = 0; j < 4; j++) {
                        float xval = ((const float*)&xj[j])[kq];
                        float z = fmaf(xval, r, o);
                        float e = __builtin_amdgcn_exp2f(-(z * z));
                        acc[j] = fmaf(z * e, w, acc[j]);
                    }
                }
            }
        }
        size_t base = (size_t)2 * Tn * DOUT + (size_t)t0 * DOUT + dout;
        #pragma unroll
        for (int j = 0; j < 4; j++) out[base + (size_t)j * DOUT] = acc[j];
    }
}

extern "C" void kernel_launch(void* const* d_in, const int* in_sizes, int n_in,
                              void* d_out, int out_size, void* d_ws, size_t ws_size,
                              hipStream_t stream) {
    const float* X        = (const float*)d_in[0];
    const float* ln_w     = (const float*)d_in[1];
    const float* ln_b     = (const float*)d_in[2];
    const float* base_w   = (const float*)d_in[3];
    const float* spline_w = (const float*)d_in[4];
    const float* scale    = (const float*)d_in[5];
    const float* transl   = (const float*)d_in[6];
    const float* grid_rbf = (const float*)d_in[7];
    const float* grid_bs  = (const float*)d_in[8];
    float* out = (float*)d_out;

    char* ws = (char*)d_ws;
    bf16*  Amat = (bf16*)ws;                                   // 16 MiB   [4096][2048]
    bf16*  SWb  = (bf16*)(ws + 16777216);                      // 2 MiB    [512][2048]
    bf16*  BWb  = (bf16*)(ws + 18874368);                      // 0.25 MiB [512][256]
    bf16*  Sm   = (bf16*)(ws + 19136512);                      // 0.5 MiB  [1024][256]
    float* Xn2  = (float*)(ws + 19660800);                     // 1 MiB    [1024][256]
    unsigned int*   roP = (unsigned int*)(ws + 20709376);      // 0.5 MiB  [32][512][8]
    unsigned short* wnP = (unsigned short*)(ws + 21233664);    // 0.25 MiB [32][512][8]

    k1_kernel<<<2176, 256, 0, stream>>>(X, ln_w, ln_b, grid_rbf, grid_bs,
                                        spline_w, base_w, scale, transl,
                                        Amat, Sm, Xn2, SWb, BWb, roP, wnP);
    k2_kernel<<<1344, 128, 0, stream>>>(Amat, SWb, Sm, BWb, Xn2, roP, wnP, out);
}